// Round 1
// baseline (374.680 us; speedup 1.0000x reference)
//
#include <hip/hip_runtime.h>
#include <math.h>

// LlamaMoETopKRouter: hidden [4,4096,4096] f32, router_weight [8,4096] f32.
// Outputs (flat concat in d_out, all viewed as float):
//   [0,        32768)  expert_weights  [B,S,2]
//   [32768,    65536)  expert_indices  [B,S,2] (written as float values)
//   [65536,   196608)  router_logits   [B,S,8]

#define H    4096
#define HV   (H / 4)      // float4 per row
#define NE   8
#define T    4            // tokens per wave
#define NTOK 16384        // 4*4096

__global__ __launch_bounds__(256, 4)
void moe_router_kernel(const float* __restrict__ hs_,
                       const float* __restrict__ rw_,
                       float* __restrict__ out) {
    const int tid  = threadIdx.x;
    const int wave = tid >> 6;
    const int lane = tid & 63;
    const int group  = blockIdx.x * 4 + wave;   // 4096 groups of T tokens
    const int token0 = group * T;

    const float4* hs = reinterpret_cast<const float4*>(hs_) + (size_t)token0 * HV;
    const float4* rw = reinterpret_cast<const float4*>(rw_);

    float acc[T][NE];
#pragma unroll
    for (int t = 0; t < T; ++t)
#pragma unroll
        for (int e = 0; e < NE; ++e) acc[t][e] = 0.0f;

    // Main loop: 16 iterations; per iter each lane loads 4 hidden float4
    // (coalesced 1 KiB/wave per token) + 8 weight float4 (L1/L2-hit).
    for (int c = 0; c < HV; c += 64) {
        const int idx = c + lane;
        float4 x0 = hs[0 * HV + idx];
        float4 x1 = hs[1 * HV + idx];
        float4 x2 = hs[2 * HV + idx];
        float4 x3 = hs[3 * HV + idx];
#pragma unroll
        for (int e = 0; e < NE; ++e) {
            float4 w = rw[e * HV + idx];
            acc[0][e] += x0.x * w.x + x0.y * w.y + x0.z * w.z + x0.w * w.w;
            acc[1][e] += x1.x * w.x + x1.y * w.y + x1.z * w.z + x1.w * w.w;
            acc[2][e] += x2.x * w.x + x2.y * w.y + x2.z * w.z + x2.w * w.w;
            acc[3][e] += x3.x * w.x + x3.y * w.y + x3.z * w.z + x3.w * w.w;
        }
    }

    // Butterfly reduce each (token, expert) partial across the 64 lanes.
#pragma unroll
    for (int t = 0; t < T; ++t)
#pragma unroll
        for (int e = 0; e < NE; ++e) {
            float v = acc[t][e];
#pragma unroll
            for (int m = 32; m > 0; m >>= 1) v += __shfl_xor(v, m, 64);
            acc[t][e] = v;
        }

    // Epilogue: lanes 0..T-1 each handle one token.
    if (lane < T) {
        float l[NE];
#pragma unroll
        for (int e = 0; e < NE; ++e) {
            float v = acc[0][e];
            if (lane == 1) v = acc[1][e];
            if (lane == 2) v = acc[2][e];
            if (lane == 3) v = acc[3][e];
            l[e] = v;
        }
        const int token = token0 + lane;

        // router_logits (raw dot products)
        float4* lg = reinterpret_cast<float4*>(out + 4 * NTOK) + (size_t)token * 2;
        lg[0] = make_float4(l[0], l[1], l[2], l[3]);
        lg[1] = make_float4(l[4], l[5], l[6], l[7]);

        // top-2 (softmax is monotone in logits; ties -> lowest index, like lax.top_k)
        float v1 = l[0]; int i1 = 0;
#pragma unroll
        for (int e = 1; e < NE; ++e)
            if (l[e] > v1) { v1 = l[e]; i1 = e; }
        float v2 = -INFINITY; int i2 = 0;
#pragma unroll
        for (int e = 0; e < NE; ++e)
            if (e != i1 && l[e] > v2) { v2 = l[e]; i2 = e; }

        // renormalized top-2 softmax weights:
        // p1/(p1+p2) = 1/(1+exp(l2-l1)), exact same math as softmax->renorm.
        const float b   = expf(v2 - v1);
        const float inv = 1.0f / (1.0f + b);
        out[token * 2 + 0] = inv;
        out[token * 2 + 1] = b * inv;

        // indices, written as float values (d_out is float-typed)
        out[2 * NTOK + token * 2 + 0] = (float)i1;
        out[2 * NTOK + token * 2 + 1] = (float)i2;
    }
}

extern "C" void kernel_launch(void* const* d_in, const int* in_sizes, int n_in,
                              void* d_out, int out_size, void* d_ws, size_t ws_size,
                              hipStream_t stream) {
    const float* hs = (const float*)d_in[0];   // [4,4096,4096] f32
    const float* rw = (const float*)d_in[1];   // [8,4096] f32
    float* out = (float*)d_out;

    // 16384 tokens / (4 waves/block * 4 tokens/wave) = 1024 blocks
    dim3 grid(NTOK / (4 * T));
    dim3 block(256);
    moe_router_kernel<<<grid, block, 0, stream>>>(hs, rw, out);
}